// Round 16
// baseline (306.891 us; speedup 1.0000x reference)
//
#include <hip/hip_runtime.h>

#define TT 100
#define HH 100
#define NL 5
#define NOUT 10
#define CC 10
#define NC (TT / CC)
#define XROW 128   // padded k length in f16 halves
#define XR2 256    // hi/lo row-pair stride in halves
#define TPB 512    // 8 waves

typedef _Float16 f16x8 __attribute__((ext_vector_type(8)));
typedef float f32x4 __attribute__((ext_vector_type(4)));

__device__ __forceinline__ float sigm(float x) { return 1.f / (1.f + __expf(-x)); }

__device__ __forceinline__ float qred(float p) {
  int t = __builtin_amdgcn_update_dpp(0, __builtin_bit_cast(int, p), 0xB1, 0xF,
                                      0xF, true);
  p += __builtin_bit_cast(float, t);
  t = __builtin_amdgcn_update_dpp(0, __builtin_bit_cast(int, p), 0x4E, 0xF, 0xF,
                                  true);
  p += __builtin_bit_cast(float, t);
  return p;
}

// HAZARD-HARDENED MFMA (R14 NaN root cause: compiler schedules VALU between
// asm stmts; inline-asm MFMA gets NO compiler hazard nops. s_nop 2 lives
// INSIDE each asm so no VALU can slip between it and the mfma.)
#define MFA(ACC, A, B)                                                   \
  asm volatile("s_nop 2\n\tv_mfma_f32_16x16x32_f16 %0, %1, %2, %0"       \
               : "+v"(ACC) : "a"(A), "v"(B));
#define MFV(ACC, A, B)                                                   \
  asm volatile("s_nop 2\n\tv_mfma_f32_16x16x32_f16 %0, %1, %2, %0"       \
               : "+v"(ACC) : "v"(A), "v"(B));
// 19 dead cycles tied into X's dep chain: MFMA-write -> VALU/DS-read guard.
#define NOPV(X) asm volatile("s_nop 7\n\ts_nop 7\n\ts_nop 2" : "+v"(X));

#define FR16(M)                                                         \
  M(0, 0) M(0, 1) M(0, 2) M(0, 3) M(1, 0) M(1, 1) M(1, 2) M(1, 3)       \
  M(2, 0) M(2, 1) M(2, 2) M(2, 3) M(3, 0) M(3, 1) M(3, 2) M(3, 3)

struct fragpair { f16x8 hi, lo; };

// load 8 fp32, split each into f16 hi + exact f16 lo residual
__device__ __forceinline__ fragpair ldfrag2(const float* base, int r, int kb) {
  f16x8 h, l;
#pragma unroll
  for (int e = 0; e < 8; ++e) {
    float v = 0.f;
    if (r < 400 && (kb + e) < 100) v = base[r * 100 + kb + e];
    _Float16 vh = (_Float16)v;
    h[e] = vh;
    l[e] = (_Float16)(v - (float)vh);
  }
  fragpair fp; fp.hi = h; fp.lo = l;
  return fp;
}

__device__ __forceinline__ f16x8 bcf(uint4 u) { return __builtin_bit_cast(f16x8, u); }

__device__ __forceinline__ unsigned pk2(_Float16 lo, _Float16 hi) {
  return (unsigned)__builtin_bit_cast(unsigned short, lo) |
         ((unsigned)__builtin_bit_cast(unsigned short, hi) << 16);
}

// ---- pre-kernel: fp32 input -> hi/lo f16 row-pairs in xst slot 0 ----
__global__ void pack_x0(const float* __restrict__ in, unsigned* __restrict__ x0) {
  for (int idx = blockIdx.x * 512 + threadIdx.x; idx < TT * (XR2 / 2);
       idx += gridDim.x * 512) {
    int t = idx >> 7, d = idx & 127;
    int k0 = 2 * (d & 63);
    unsigned v = 0u;
    if (k0 < 100) {
      float a = in[t * HH + k0], b = in[t * HH + k0 + 1];
      _Float16 ah = (_Float16)a, bh = (_Float16)b;
      if (d < 64) v = pk2(ah, bh);
      else v = pk2((_Float16)(a - (float)ah), (_Float16)(b - (float)bh));
    }
    x0[idx] = v;
  }
}

// ---- main: one block per layer. FULL EFT (error ~1e-7, deterministic pass):
// Whh hi+lo AGPR-resident; h,x hi/lo; Wih hi+lo built per chunk (hazard-safe).
// Step: B col s = h_hi, col LC = h_lo; 2 A-passes (Whi,Wlo) give all 4
// EFT cross products; activation sums the two D-columns.
__global__ __attribute__((amdgpu_flat_work_group_size(TPB, TPB),
                          amdgpu_waves_per_eu(2, 2)))
void lstm_pipe_kernel(
    const float* __restrict__ Wih,   // [L, 4H, H]
    const float* __restrict__ Whh,   // [L, 4H, H]
    const float* __restrict__ bih,   // [L, 4H]
    const float* __restrict__ bhh,   // [L, 4H]
    const float* __restrict__ Wout,  // [OUT, H]
    const float* __restrict__ bout,  // [OUT]
    float* __restrict__ out,         // [T, OUT]
    int* __restrict__ flags,         // [L-1, NC]
    unsigned short* __restrict__ xst)  // [NL][TT][XR2] hi/lo f16 row-pairs
{
  __shared__ __align__(16) unsigned short xch[CC * XR2];
  __shared__ __align__(16) unsigned short och16[CC * XR2];
  __shared__ __align__(16) unsigned short hbuf[2 * XR2];
  __shared__ __align__(16) float gsumS[512];  // D col s  (W * h_hi)
  __shared__ __align__(16) float gsumL[512];  // D col LC (W * h_lo)
  __shared__ __align__(16) float ochf[CC * HH];

  const int l = blockIdx.x;
  const int tid = threadIdx.x;
  const int lane = tid & 63;
  const int w4 = (tid >> 6) * 4;     // first row-tile of this wave
  const int row16 = lane & 15;       // A row within tile
  const int col = lane & 15;         // B/D column
  const int kg8 = (lane >> 4) << 3;  // k-group offset (halves)
  const int kg4 = (lane >> 4) << 2;  // D row-group offset

  const float* WhhL = Whh + (size_t)l * 40000;
  const float* WihL = Wih + (size_t)l * 40000;

  // ---- Whh hi/lo fragments -> AGPR (32 x f16x8 = 128 regs) ----
#define DW(t, k) f16x8 WHH##t##k, WHL##t##k;
  FR16(DW)
#define LDW(t, k)                                                          \
  { fragpair fp_ = ldfrag2(WhhL, (w4 + (t)) * 16 + row16, (k) * 32 + kg8); \
    WHH##t##k = fp_.hi; WHL##t##k = fp_.lo; }
  FR16(LDW)

  float bi0 = 0.f, bi1 = 0.f, bi2 = 0.f, bi3 = 0.f, cc_ = 0.f;
  if (tid < HH) {
    bi0 = bih[l * 400 + tid] + bhh[l * 400 + tid];
    bi1 = bih[l * 400 + 100 + tid] + bhh[l * 400 + 100 + tid];
    bi2 = bih[l * 400 + 200 + tid] + bhh[l * 400 + 200 + tid];
    bi3 = bih[l * 400 + 300 + tid] + bhh[l * 400 + 300 + tid];
  }
  if (tid < 64) ((uint4*)hbuf)[tid] = make_uint4(0u, 0u, 0u, 0u);
  if (tid < 320) ((uint4*)och16)[tid] = make_uint4(0u, 0u, 0u, 0u);
  __syncthreads();

  for (int ch = 0; ch < NC; ++ch) {
    // ---- acquire x chunk (hi/lo) into LDS ----
    if (l > 0) {
      if (tid == 0) {
        const int* fl = flags + (l - 1) * NC + ch;
        while (__hip_atomic_load(fl, __ATOMIC_ACQUIRE, __HIP_MEMORY_SCOPE_AGENT) == 0)
          __builtin_amdgcn_s_sleep(1);
      }
      __syncthreads();
    }
    {
      const uint4* src = (const uint4*)(xst + ((size_t)l * TT + ch * CC) * XR2);
      if (tid < 320) ((uint4*)xch)[tid] = src[tid];
    }
    __syncthreads();

    // ---- chunk batch: XA cols 0..9 = full EFT Wih @ x (hi/lo) ----
    f32x4 XA0 = {0.f, 0.f, 0.f, 0.f}, XA1 = {0.f, 0.f, 0.f, 0.f};
    f32x4 XA2 = {0.f, 0.f, 0.f, 0.f}, XA3 = {0.f, 0.f, 0.f, 0.f};
    {
      uint4 z4 = make_uint4(0u, 0u, 0u, 0u);
      uint4 u0 = z4, u1 = z4, u2 = z4, u3 = z4;
      uint4 v0 = z4, v1 = z4, v2 = z4, v3 = z4;
      if (col < CC) {
        const unsigned short* xph = xch + col * XR2 + kg8;
        const unsigned short* xpl = xph + XROW;
        u0 = *(const uint4*)(xph + 0);  u1 = *(const uint4*)(xph + 32);
        u2 = *(const uint4*)(xph + 64); u3 = *(const uint4*)(xph + 96);
        v0 = *(const uint4*)(xpl + 0);  v1 = *(const uint4*)(xpl + 32);
        v2 = *(const uint4*)(xpl + 64); v3 = *(const uint4*)(xpl + 96);
      }
      f16x8 Xh0 = bcf(u0), Xh1 = bcf(u1), Xh2 = bcf(u2), Xh3 = bcf(u3);
      f16x8 Xl0 = bcf(v0), Xl1 = bcf(v1), Xl2 = bcf(v2), Xl3 = bcf(v3);
#define XAT(t)                                                           \
      if (w4 + (t) < 25) {                                               \
        const int rr = (w4 + (t)) * 16 + row16;                          \
        fragpair f0 = ldfrag2(WihL, rr, 0 + kg8);                        \
        fragpair f1 = ldfrag2(WihL, rr, 32 + kg8);                       \
        fragpair f2 = ldfrag2(WihL, rr, 64 + kg8);                       \
        fragpair f3 = ldfrag2(WihL, rr, 96 + kg8);                       \
        MFV(XA##t, f0.hi, Xh0) MFV(XA##t, f1.hi, Xh1)                    \
        MFV(XA##t, f2.hi, Xh2) MFV(XA##t, f3.hi, Xh3)                    \
        MFV(XA##t, f0.lo, Xh0) MFV(XA##t, f1.lo, Xh1)                    \
        MFV(XA##t, f2.lo, Xh2) MFV(XA##t, f3.lo, Xh3)                    \
        MFV(XA##t, f0.hi, Xl0) MFV(XA##t, f1.hi, Xl1)                    \
        MFV(XA##t, f2.hi, Xl2) MFV(XA##t, f3.hi, Xl3)                    \
        MFV(XA##t, f0.lo, Xl0) MFV(XA##t, f1.lo, Xl1)                    \
        MFV(XA##t, f2.lo, Xl2) MFV(XA##t, f3.lo, Xl3)                    \
        NOPV(XA##t)                                                      \
      }
      XAT(0) XAT(1) XAT(2) XAT(3)
    }

    // ---- CC recurrent steps ----
#define TILEC(t, s, LCv)                                                 \
      if (w4 + (t) < 25) {                                               \
        f32x4 dd = XA##t;                                                \
        MFA(dd, WHH##t##0, fB0) MFA(dd, WHH##t##1, fB1)                  \
        MFA(dd, WHH##t##2, fB2) MFA(dd, WHH##t##3, fB3)                  \
        MFA(dd, WHL##t##0, fB0) MFA(dd, WHL##t##1, fB1)                  \
        MFA(dd, WHL##t##2, fB2) MFA(dd, WHL##t##3, fB3)                  \
        NOPV(dd)                                                         \
        const int rbt = (w4 + (t)) * 16 + kg4;                           \
        if (col == (s)) *(f32x4*)(gsumS + rbt) = dd;                     \
        else if (col == (LCv)) *(f32x4*)(gsumL + rbt) = dd;              \
      }
#define STEP(s)                                                               \
    {                                                                         \
      const int p = (s) & 1;                                                  \
      const int LCv = 10 + ((s) % 6);                                         \
      const unsigned short* hph = hbuf + p * XR2 + kg8;                       \
      const unsigned short* hpl = hph + XROW;                                 \
      uint4 z4s = make_uint4(0u, 0u, 0u, 0u);                                 \
      uint4 q0 = z4s, q1 = z4s, q2 = z4s, q3 = z4s;                           \
      if (col == (s)) {                                                       \
        q0 = *(const uint4*)(hph + 0);  q1 = *(const uint4*)(hph + 32);       \
        q2 = *(const uint4*)(hph + 64); q3 = *(const uint4*)(hph + 96);       \
      } else if (col == LCv) {                                                \
        q0 = *(const uint4*)(hpl + 0);  q1 = *(const uint4*)(hpl + 32);       \
        q2 = *(const uint4*)(hpl + 64); q3 = *(const uint4*)(hpl + 96);       \
      }                                                                       \
      f16x8 fB0 = bcf(q0), fB1 = bcf(q1), fB2 = bcf(q2), fB3 = bcf(q3);       \
      TILEC(0, s, LCv) TILEC(1, s, LCv) TILEC(2, s, LCv) TILEC(3, s, LCv)     \
      __syncthreads(); /* gsum complete */                                    \
      if (tid < HH) {                                                         \
        float s0 = gsumS[tid] + gsumL[tid] + bi0;                             \
        float s1 = gsumS[100 + tid] + gsumL[100 + tid] + bi1;                 \
        float s2 = gsumS[200 + tid] + gsumL[200 + tid] + bi2;                 \
        float s3 = gsumS[300 + tid] + gsumL[300 + tid] + bi3;                 \
        float gi = sigm(s0), gf = sigm(s1);                                   \
        float gv = 2.f * sigm(2.f * s2) - 1.f, go = sigm(s3);                 \
        cc_ = gf * cc_ + gi * gv;                                             \
        float h = go * (2.f * sigm(2.f * cc_) - 1.f);                         \
        _Float16 hhi = (_Float16)h;                                           \
        _Float16 hlo = (_Float16)(h - (float)hhi);                            \
        hbuf[(p ^ 1) * XR2 + tid] = __builtin_bit_cast(unsigned short, hhi);  \
        hbuf[(p ^ 1) * XR2 + XROW + tid] =                                    \
            __builtin_bit_cast(unsigned short, hlo);                          \
        if (l < NL - 1) {                                                     \
          float hr = fmaxf(h, 0.f);                                           \
          _Float16 rhi = (_Float16)hr;                                        \
          _Float16 rlo = (_Float16)(hr - (float)rhi);                         \
          och16[(s) * XR2 + tid] = __builtin_bit_cast(unsigned short, rhi);   \
          och16[(s) * XR2 + XROW + tid] =                                     \
              __builtin_bit_cast(unsigned short, rlo);                        \
        } else {                                                              \
          ochf[(s) * HH + tid] = h;                                           \
        }                                                                     \
      }                                                                       \
      __syncthreads(); /* h ready; gsum consumed */                           \
    }
    STEP(0) STEP(1) STEP(2) STEP(3) STEP(4)
    STEP(5) STEP(6) STEP(7) STEP(8) STEP(9)

    if (l < NL - 1) {
      // ---- publish chunk (hi/lo): coalesced write + fence + flag ----
      uint4* dst = (uint4*)(xst + ((size_t)(l + 1) * TT + ch * CC) * XR2);
      if (tid < 320) dst[tid] = ((const uint4*)och16)[tid];
      __syncthreads();
      if (tid == 0) {
        __threadfence();
        __hip_atomic_store(flags + l * NC + ch, 1, __ATOMIC_RELEASE,
                           __HIP_MEMORY_SCOPE_AGENT);
      }
    } else {
      // ---- batched output projection (fp32) ----
      if (tid < 400) {
        int j = tid >> 2, q = tid & 3;
        int s2 = j / 10, r = j % 10;
        const float* wrow = Wout + r * HH + q * 25;
        const float* hrow = ochf + s2 * HH + q * 25;
        float acc = 0.f;
#pragma unroll
        for (int m2 = 0; m2 < 25; ++m2) acc = fmaf(wrow[m2], hrow[m2], acc);
        acc = qred(acc);
        if (q == 0) out[(ch * CC + s2) * NOUT + r] = sigm(acc + bout[r]);
      }
      __syncthreads();  // ochf reused next chunk
    }
  }
}

extern "C" void kernel_launch(void* const* d_in, const int* in_sizes, int n_in,
                              void* d_out, int out_size, void* d_ws, size_t ws_size,
                              hipStream_t stream) {
  const float* input = (const float*)d_in[0];
  const float* Wih   = (const float*)d_in[1];
  const float* Whh   = (const float*)d_in[2];
  const float* bih   = (const float*)d_in[3];
  const float* bhh   = (const float*)d_in[4];
  const float* Wout  = (const float*)d_in[5];
  const float* bout  = (const float*)d_in[6];
  float* out = (float*)d_out;

  // ws layout (bytes):
  //   [0, 2048)        flags ((L-1)*NC = 40 ints used)
  //   [2048, 258048)   xst: NL*TT*XR2 halves = 5*100*256*2 = 256000
  int* flags = (int*)d_ws;
  unsigned short* xst = (unsigned short*)((char*)d_ws + 2048);

  // flags must be zero at kernel start on EVERY call (graph replays included)
  hipMemsetAsync(d_ws, 0, 2048, stream);

  pack_x0<<<dim3(8), dim3(512), 0, stream>>>(input, (unsigned*)xst);

  lstm_pipe_kernel<<<dim3(NL), dim3(TPB), 0, stream>>>(
      Wih, Whh, bih, bhh, Wout, bout, out, flags, xst);
}

// Round 17
// 287.678 us; speedup vs baseline: 1.0668x; 1.0668x over previous
//
#include <hip/hip_runtime.h>

#define TT 100
#define HH 100
#define NL 5
#define NOUT 10
#define CC 10
#define NC (TT / CC)
#define XROW 128   // padded k length in f16 halves
#define XR2 256    // hi/lo row-pair stride in halves
#define TPB 512    // 8 waves

typedef _Float16 f16x8 __attribute__((ext_vector_type(8)));
typedef float f32x4 __attribute__((ext_vector_type(4)));

__device__ __forceinline__ float sigm(float x) { return 1.f / (1.f + __expf(-x)); }

__device__ __forceinline__ float qred(float p) {
  int t = __builtin_amdgcn_update_dpp(0, __builtin_bit_cast(int, p), 0xB1, 0xF,
                                      0xF, true);
  p += __builtin_bit_cast(float, t);
  t = __builtin_amdgcn_update_dpp(0, __builtin_bit_cast(int, p), 0x4E, 0xF, 0xF,
                                  true);
  p += __builtin_bit_cast(float, t);
  return p;
}

// FUSED 8-MFMA tile chain, two accumulators interleaved (dep distance 2).
// Head s_nop 2: covers VALU(acc init / B cndmask) -> MFMA read.
// Tail s_nop 7,7,1: covers MFMA write -> VALU/DS read of the accumulators.
// All inside ONE asm: compiler cannot interpose VALU (R14's NaN class).
#define TFULL(DA, DB, A0, A1, A2, A3, C0, C1, C2, C3, B0, B1, B2, B3)       \
  asm("s_nop 2\n\t"                                                         \
      "v_mfma_f32_16x16x32_f16 %0, %2, %10, %0\n\t"                         \
      "v_mfma_f32_16x16x32_f16 %1, %6, %10, %1\n\t"                         \
      "v_mfma_f32_16x16x32_f16 %0, %3, %11, %0\n\t"                         \
      "v_mfma_f32_16x16x32_f16 %1, %7, %11, %1\n\t"                         \
      "v_mfma_f32_16x16x32_f16 %0, %4, %12, %0\n\t"                         \
      "v_mfma_f32_16x16x32_f16 %1, %8, %12, %1\n\t"                         \
      "v_mfma_f32_16x16x32_f16 %0, %5, %13, %0\n\t"                         \
      "v_mfma_f32_16x16x32_f16 %1, %9, %13, %1\n\t"                         \
      "s_nop 7\n\ts_nop 7\n\ts_nop 1"                                       \
      : "+v"(DA), "+v"(DB)                                                  \
      : "a"(A0), "a"(A1), "a"(A2), "a"(A3),                                 \
        "a"(C0), "a"(C1), "a"(C2), "a"(C3),                                 \
        "v"(B0), "v"(B1), "v"(B2), "v"(B3));

#define FR16(M)                                                         \
  M(0, 0) M(0, 1) M(0, 2) M(0, 3) M(1, 0) M(1, 1) M(1, 2) M(1, 3)       \
  M(2, 0) M(2, 1) M(2, 2) M(2, 3) M(3, 0) M(3, 1) M(3, 2) M(3, 3)

struct fragpair { f16x8 hi, lo; };

// load 8 fp32, split each into f16 hi + exact f16 lo residual (init only)
__device__ __forceinline__ fragpair ldfrag2(const float* base, int r, int kb) {
  f16x8 h, l;
#pragma unroll
  for (int e = 0; e < 8; ++e) {
    float v = 0.f;
    if (r < 400 && (kb + e) < 100) v = base[r * 100 + kb + e];
    _Float16 vh = (_Float16)v;
    h[e] = vh;
    l[e] = (_Float16)(v - (float)vh);
  }
  fragpair fp; fp.hi = h; fp.lo = l;
  return fp;
}

__device__ __forceinline__ f16x8 bcf(uint4 u) { return __builtin_bit_cast(f16x8, u); }

__device__ __forceinline__ unsigned pk2(_Float16 lo, _Float16 hi) {
  return (unsigned)__builtin_bit_cast(unsigned short, lo) |
         ((unsigned)__builtin_bit_cast(unsigned short, hi) << 16);
}

// ---- pre-kernel 1: fp32 input -> hi/lo f16 row-pairs in xst slot 0 ----
__global__ void pack_x0(const float* __restrict__ in, unsigned* __restrict__ x0) {
  for (int idx = blockIdx.x * 512 + threadIdx.x; idx < TT * (XR2 / 2);
       idx += gridDim.x * 512) {
    int t = idx >> 7, d = idx & 127;
    int k0 = 2 * (d & 63);
    unsigned v = 0u;
    if (k0 < 100) {
      float a = in[t * HH + k0], b = in[t * HH + k0 + 1];
      _Float16 ah = (_Float16)a, bh = (_Float16)b;
      if (d < 64) v = pk2(ah, bh);
      else v = pk2((_Float16)(a - (float)ah), (_Float16)(b - (float)bh));
    }
    x0[idx] = v;
  }
}

// ---- pre-kernel 2: Wih -> per-lane hi/lo MFMA A-fragments (coalesced) ----
// layout: [(l*25 + tile)*4 + kb][lane] of uint4 (= f16x8 fragment)
__global__ void pack_wi(const float* __restrict__ Wih, uint4* __restrict__ wifh,
                        uint4* __restrict__ wifl) {
  const int b = blockIdx.x;  // l*25 + tile
  const int l = b / 25, t = b % 25;
  const int kb = threadIdx.x >> 6, lane = threadIdx.x & 63;
  const int r = t * 16 + (lane & 15);
  const int k0 = kb * 32 + ((lane >> 4) << 3);
  f16x8 h, lo;
#pragma unroll
  for (int e = 0; e < 8; ++e) {
    float v = 0.f;
    if (k0 + e < 100) v = Wih[((size_t)l * 400 + r) * 100 + k0 + e];
    _Float16 vh = (_Float16)v;
    h[e] = vh;
    lo[e] = (_Float16)(v - (float)vh);
  }
  wifh[((size_t)b * 4 + kb) * 64 + lane] = __builtin_bit_cast(uint4, h);
  wifl[((size_t)b * 4 + kb) * 64 + lane] = __builtin_bit_cast(uint4, lo);
}

// ---- main: one block per layer. FULL EFT (R15-exact math, absmax 0.0):
// Whh hi/lo AGPR-resident; Wih fragments pre-packed (8 coalesced loads/tile);
// fused-chain asm (8 MFMA, 2 chains, nops only at head/tail).
__global__ __attribute__((amdgpu_flat_work_group_size(TPB, TPB),
                          amdgpu_waves_per_eu(2, 2)))
void lstm_pipe_kernel(
    const float* __restrict__ Whh,   // [L, 4H, H]
    const float* __restrict__ bih,   // [L, 4H]
    const float* __restrict__ bhh,   // [L, 4H]
    const float* __restrict__ Wout,  // [OUT, H]
    const float* __restrict__ bout,  // [OUT]
    float* __restrict__ out,         // [T, OUT]
    int* __restrict__ flags,         // [L-1, NC]
    unsigned short* __restrict__ xst,  // [NL][TT][XR2] hi/lo f16 row-pairs
    const uint4* __restrict__ wifh,  // packed Wih hi fragments
    const uint4* __restrict__ wifl)  // packed Wih lo fragments
{
  __shared__ __align__(16) unsigned short xch[CC * XR2];
  __shared__ __align__(16) unsigned short och16[CC * XR2];
  __shared__ __align__(16) unsigned short hbuf[2 * XR2];
  __shared__ __align__(16) float gsumS[512];  // D col s  (W * h_hi)
  __shared__ __align__(16) float gsumL[512];  // D col LC (W * h_lo)
  __shared__ __align__(16) float ochf[CC * HH];

  const int l = blockIdx.x;
  const int tid = threadIdx.x;
  const int lane = tid & 63;
  const int w4 = (tid >> 6) * 4;     // first row-tile of this wave
  const int row16 = lane & 15;       // A row within tile
  const int col = lane & 15;         // B/D column
  const int kg8 = (lane >> 4) << 3;  // k-group offset (halves)
  const int kg4 = (lane >> 4) << 2;  // D row-group offset

  const float* WhhL = Whh + (size_t)l * 40000;

  // ---- Whh hi/lo fragments -> AGPR (32 x f16x8 = 128 regs), init once ----
#define DW(t, k) f16x8 WHH##t##k, WHL##t##k;
  FR16(DW)
#define LDW(t, k)                                                          \
  { fragpair fp_ = ldfrag2(WhhL, (w4 + (t)) * 16 + row16, (k) * 32 + kg8); \
    WHH##t##k = fp_.hi; WHL##t##k = fp_.lo; }
  FR16(LDW)

  float bi0 = 0.f, bi1 = 0.f, bi2 = 0.f, bi3 = 0.f, cc_ = 0.f;
  if (tid < HH) {
    bi0 = bih[l * 400 + tid] + bhh[l * 400 + tid];
    bi1 = bih[l * 400 + 100 + tid] + bhh[l * 400 + 100 + tid];
    bi2 = bih[l * 400 + 200 + tid] + bhh[l * 400 + 200 + tid];
    bi3 = bih[l * 400 + 300 + tid] + bhh[l * 400 + 300 + tid];
  }
  if (tid < 64) ((uint4*)hbuf)[tid] = make_uint4(0u, 0u, 0u, 0u);
  if (tid < 320) ((uint4*)och16)[tid] = make_uint4(0u, 0u, 0u, 0u);
  __syncthreads();

  for (int ch = 0; ch < NC; ++ch) {
    // ---- acquire x chunk (hi/lo) into LDS ----
    if (l > 0) {
      if (tid == 0) {
        const int* fl = flags + (l - 1) * NC + ch;
        while (__hip_atomic_load(fl, __ATOMIC_ACQUIRE, __HIP_MEMORY_SCOPE_AGENT) == 0)
          __builtin_amdgcn_s_sleep(1);
      }
      __syncthreads();
    }
    {
      const uint4* src = (const uint4*)(xst + ((size_t)l * TT + ch * CC) * XR2);
      if (tid < 320) ((uint4*)xch)[tid] = src[tid];
    }
    __syncthreads();

    // ---- chunk batch: XA cols 0..9 = full EFT Wih @ x (prepacked frags) ----
    f32x4 XA0, XA1, XA2, XA3;
    {
      uint4 z4 = make_uint4(0u, 0u, 0u, 0u);
      uint4 u0 = z4, u1 = z4, u2 = z4, u3 = z4;
      uint4 v0 = z4, v1 = z4, v2 = z4, v3 = z4;
      if (col < CC) {
        const unsigned short* xph = xch + col * XR2 + kg8;
        const unsigned short* xpl = xph + XROW;
        u0 = *(const uint4*)(xph + 0);  u1 = *(const uint4*)(xph + 32);
        u2 = *(const uint4*)(xph + 64); u3 = *(const uint4*)(xph + 96);
        v0 = *(const uint4*)(xpl + 0);  v1 = *(const uint4*)(xpl + 32);
        v2 = *(const uint4*)(xpl + 64); v3 = *(const uint4*)(xpl + 96);
      }
      f16x8 Xh0 = bcf(u0), Xh1 = bcf(u1), Xh2 = bcf(u2), Xh3 = bcf(u3);
      f16x8 Xl0 = bcf(v0), Xl1 = bcf(v1), Xl2 = bcf(v2), Xl3 = bcf(v3);
#define XAT(t)                                                            \
      {                                                                   \
        const int ti = (w4 + (t) < 25) ? (w4 + (t)) : 0;                  \
        const uint4* fp = wifh + (((size_t)l * 25 + ti) * 4) * 64 + lane; \
        const uint4* gp = wifl + (((size_t)l * 25 + ti) * 4) * 64 + lane; \
        f16x8 Fh0 = bcf(fp[0]), Fh1 = bcf(fp[64]);                        \
        f16x8 Fh2 = bcf(fp[128]), Fh3 = bcf(fp[192]);                     \
        f16x8 Fl0 = bcf(gp[0]), Fl1 = bcf(gp[64]);                        \
        f16x8 Fl2 = bcf(gp[128]), Fl3 = bcf(gp[192]);                     \
        f32x4 xa = {0.f, 0.f, 0.f, 0.f}, xb = {0.f, 0.f, 0.f, 0.f};       \
        if (w4 + (t) < 25) {                                              \
          TFULL(xa, xb, Fh0, Fh1, Fh2, Fh3, Fl0, Fl1, Fl2, Fl3,           \
                Xh0, Xh1, Xh2, Xh3)                                       \
          TFULL(xa, xb, Fh0, Fh1, Fh2, Fh3, Fl0, Fl1, Fl2, Fl3,           \
                Xl0, Xl1, Xl2, Xl3)                                       \
        }                                                                 \
        XA##t = xa + xb;                                                  \
      }
      XAT(0) XAT(1) XAT(2) XAT(3)
    }

    // ---- CC recurrent steps ----
#define TILEC(t, s, LCv)                                                  \
      if (w4 + (t) < 25) {                                                \
        f32x4 dda = XA##t, ddb = {0.f, 0.f, 0.f, 0.f};                    \
        TFULL(dda, ddb, WHH##t##0, WHH##t##1, WHH##t##2, WHH##t##3,       \
              WHL##t##0, WHL##t##1, WHL##t##2, WHL##t##3,                 \
              fB0, fB1, fB2, fB3)                                         \
        f32x4 dd = dda + ddb;                                             \
        const int rbt = (w4 + (t)) * 16 + kg4;                            \
        if (col == (s)) *(f32x4*)(gsumS + rbt) = dd;                      \
        else if (col == (LCv)) *(f32x4*)(gsumL + rbt) = dd;               \
      }
#define STEP(s)                                                               \
    {                                                                         \
      const int p = (s) & 1;                                                  \
      const int LCv = 10 + ((s) % 6);                                         \
      const unsigned short* hph = hbuf + p * XR2 + kg8;                       \
      const unsigned short* hpl = hph + XROW;                                 \
      uint4 z4s = make_uint4(0u, 0u, 0u, 0u);                                 \
      uint4 q0 = z4s, q1 = z4s, q2 = z4s, q3 = z4s;                           \
      if (col == (s)) {                                                       \
        q0 = *(const uint4*)(hph + 0);  q1 = *(const uint4*)(hph + 32);       \
        q2 = *(const uint4*)(hph + 64); q3 = *(const uint4*)(hph + 96);       \
      } else if (col == LCv) {                                                \
        q0 = *(const uint4*)(hpl + 0);  q1 = *(const uint4*)(hpl + 32);       \
        q2 = *(const uint4*)(hpl + 64); q3 = *(const uint4*)(hpl + 96);       \
      }                                                                       \
      f16x8 fB0 = bcf(q0), fB1 = bcf(q1), fB2 = bcf(q2), fB3 = bcf(q3);       \
      TILEC(0, s, LCv) TILEC(1, s, LCv) TILEC(2, s, LCv) TILEC(3, s, LCv)     \
      __syncthreads(); /* gsum complete */                                    \
      if (tid < HH) {                                                         \
        float s0 = gsumS[tid] + gsumL[tid] + bi0;                             \
        float s1 = gsumS[100 + tid] + gsumL[100 + tid] + bi1;                 \
        float s2 = gsumS[200 + tid] + gsumL[200 + tid] + bi2;                 \
        float s3 = gsumS[300 + tid] + gsumL[300 + tid] + bi3;                 \
        float gi = sigm(s0), gf = sigm(s1);                                   \
        float gv = 2.f * sigm(2.f * s2) - 1.f, go = sigm(s3);                 \
        cc_ = gf * cc_ + gi * gv;                                             \
        float h = go * (2.f * sigm(2.f * cc_) - 1.f);                         \
        _Float16 hhi = (_Float16)h;                                           \
        _Float16 hlo = (_Float16)(h - (float)hhi);                            \
        hbuf[(p ^ 1) * XR2 + tid] = __builtin_bit_cast(unsigned short, hhi);  \
        hbuf[(p ^ 1) * XR2 + XROW + tid] =                                    \
            __builtin_bit_cast(unsigned short, hlo);                          \
        if (l < NL - 1) {                                                     \
          float hr = fmaxf(h, 0.f);                                           \
          _Float16 rhi = (_Float16)hr;                                        \
          _Float16 rlo = (_Float16)(hr - (float)rhi);                         \
          och16[(s) * XR2 + tid] = __builtin_bit_cast(unsigned short, rhi);   \
          och16[(s) * XR2 + XROW + tid] =                                     \
              __builtin_bit_cast(unsigned short, rlo);                        \
        } else {                                                              \
          ochf[(s) * HH + tid] = h;                                           \
        }                                                                     \
      }                                                                       \
      __syncthreads(); /* h ready; gsum consumed */                           \
    }
    STEP(0) STEP(1) STEP(2) STEP(3) STEP(4)
    STEP(5) STEP(6) STEP(7) STEP(8) STEP(9)

    if (l < NL - 1) {
      // ---- publish chunk (hi/lo): coalesced write + fence + flag ----
      uint4* dst = (uint4*)(xst + ((size_t)(l + 1) * TT + ch * CC) * XR2);
      if (tid < 320) dst[tid] = ((const uint4*)och16)[tid];
      __syncthreads();
      if (tid == 0) {
        __threadfence();
        __hip_atomic_store(flags + l * NC + ch, 1, __ATOMIC_RELEASE,
                           __HIP_MEMORY_SCOPE_AGENT);
      }
    } else {
      // ---- batched output projection (fp32) ----
      if (tid < 400) {
        int j = tid >> 2, q = tid & 3;
        int s2 = j / 10, r = j % 10;
        const float* wrow = Wout + r * HH + q * 25;
        const float* hrow = ochf + s2 * HH + q * 25;
        float acc = 0.f;
#pragma unroll
        for (int m2 = 0; m2 < 25; ++m2) acc = fmaf(wrow[m2], hrow[m2], acc);
        acc = qred(acc);
        if (q == 0) out[(ch * CC + s2) * NOUT + r] = sigm(acc + bout[r]);
      }
      __syncthreads();  // ochf reused next chunk
    }
  }
}

extern "C" void kernel_launch(void* const* d_in, const int* in_sizes, int n_in,
                              void* d_out, int out_size, void* d_ws, size_t ws_size,
                              hipStream_t stream) {
  const float* input = (const float*)d_in[0];
  const float* Wih   = (const float*)d_in[1];
  const float* Whh   = (const float*)d_in[2];
  const float* bih   = (const float*)d_in[3];
  const float* bhh   = (const float*)d_in[4];
  const float* Wout  = (const float*)d_in[5];
  const float* bout  = (const float*)d_in[6];
  float* out = (float*)d_out;

  // ws layout (bytes):
  //   [0, 2048)            flags ((L-1)*NC = 40 ints used)
  //   [2048, 258048)       xst: NL*TT*XR2 halves = 256000
  //   [258048, 770048)     wifh: 5*25*4*64 uint4 = 512000
  //   [770048, 1282048)    wifl: 512000
  int* flags = (int*)d_ws;
  unsigned short* xst = (unsigned short*)((char*)d_ws + 2048);
  uint4* wifh = (uint4*)((char*)d_ws + 258048);
  uint4* wifl = (uint4*)((char*)d_ws + 770048);

  // flags must be zero at kernel start on EVERY call (graph replays included)
  hipMemsetAsync(d_ws, 0, 2048, stream);

  pack_x0<<<dim3(8), dim3(512), 0, stream>>>(input, (unsigned*)xst);
  pack_wi<<<dim3(NL * 25), dim3(256), 0, stream>>>(Wih, wifh, wifl);

  lstm_pipe_kernel<<<dim3(NL), dim3(TPB), 0, stream>>>(
      Whh, bih, bhh, Wout, bout, out, flags, xst, wifh, wifl);
}